// Round 1
// baseline (2689.205 us; speedup 1.0000x reference)
//
#include <hip/hip_runtime.h>
#include <hip/hip_bf16.h>
#include <stdint.h>
#include <string.h>

// Problem constants
#define S_LEN 512
#define NBATCH 64
#define EDIM 128
#define HDIM 256
#define GDIM 1024  // 4*H

typedef __attribute__((ext_vector_type(8))) short short8;   // 8 bf16 (4 VGPRs) MFMA frag
typedef __attribute__((ext_vector_type(4))) short short4v;  // 4 bf16
typedef __attribute__((ext_vector_type(4))) float float4v;  // MFMA acc

// Workspace layout (bytes)
#define OFF_WHH 0u
#define SZ_WHH (64u * 8u * 64u * 16u)        // 512 KB: W_hh_f bf16 B-frags
#define OFF_WIH (OFF_WHH + SZ_WHH)
#define SZ_WIH (64u * 4u * 64u * 16u)        // 256 KB: W_ih_f bf16 B-frags
#define OFF_XG ((size_t)(OFF_WIH + SZ_WIH))
#define SZ_XG ((size_t)S_LEN * 4 * 64 * 64 * 8)  // 67 MB: xg_f bf16, fragment layout
#define OFF_HF (OFF_XG + SZ_XG)              // 64 KB: h_f final, fp32 [64][256]

__device__ __forceinline__ short f2bf(float f) {
    union { float f; unsigned u; } v;
    v.f = f;
    unsigned r = (v.u + 0x7fffu + ((v.u >> 16) & 1u)) >> 16;  // RNE
    return (short)r;
}
__device__ __forceinline__ float bf2f(short s) {
    union { unsigned u; float f; } v;
    v.u = ((unsigned)(unsigned short)s) << 16;
    return v.f;
}
__device__ __forceinline__ float sigm(float x) {
    float e = __expf(-x);                    // v_exp
    return __builtin_amdgcn_rcpf(1.0f + e);  // v_rcp
}
__device__ __forceinline__ float tanh_(float x) {
    float e = __expf(2.0f * x);              // overflow -> inf -> rcp 0 -> +1; underflow -> -1
    return 1.0f - 2.0f * __builtin_amdgcn_rcpf(e + 1.0f);
}

// ---------------------------------------------------------------------------
// Prep: fp32 weight [G,K] -> bf16 MFMA B-fragment layout.
// Fragment f = tile*nchunks + c; lane holds B[k = c*32+(lane>>4)*8 + j][n = lane&15]
// where gate row = tile*16 + n. Stored as 16B per (frag,lane).
// ---------------------------------------------------------------------------
__global__ __launch_bounds__(256) void prep_frags(const float* __restrict__ src,
                                                  char* __restrict__ dst,
                                                  int K, int nchunks, int nfrags) {
    int id = blockIdx.x * blockDim.x + threadIdx.x;
    int lane = id & 63;
    int f = id >> 6;
    if (f >= nfrags) return;
    int tile = f / nchunks;
    int c = f - tile * nchunks;
    int row = tile * 16 + (lane & 15);
    int k0 = c * 32 + ((lane >> 4) * 8);
    const float* s = src + (size_t)row * K + k0;
    short8 pack;
#pragma unroll
    for (int j = 0; j < 8; ++j) pack[j] = f2bf(s[j]);
    *(short8*)(dst + ((size_t)f * 64 + lane) * 16) = pack;
}

// ---------------------------------------------------------------------------
// Input projection: xg_f[t, b, gate] = x[t,b,:] @ W_ih_f^T + b_f, stored bf16 in
// MFMA C/D fragment layout: xg[((t*4+g)*64 + tile)*512 + lane*8] = 4 bf16.
// One block = 4 timesteps x 1 batch-group(16). 4 waves, wave w does N-tiles w*16..w*16+15.
// ---------------------------------------------------------------------------
__global__ __launch_bounds__(256) void input_proj(const int* __restrict__ seq,
                                                  const float* __restrict__ emb,
                                                  const char* __restrict__ wih_frags,
                                                  const float* __restrict__ bias,
                                                  char* __restrict__ xg) {
    __shared__ __align__(16) short lx[4][16][136];  // bf16 x-tiles, +8 pad
    int tid = threadIdx.x;
    int t0 = blockIdx.x * 4;
    int g = blockIdx.y;

    // stage x: 64 rows (4 t x 16 batch), 4 threads/row, 32 elems each
    {
        int row = tid >> 2;
        int tt = row >> 4, m = row & 15;
        int k0 = (tid & 3) * 32;
        int v = seq[(t0 + tt) * NBATCH + g * 16 + m];
        const float* src = emb + (size_t)v * EDIM + k0;
        bool zero = (v == 0);
#pragma unroll
        for (int u = 0; u < 32; u += 4) {
            float4v f = *(const float4v*)(src + u);
            short4v p;
#pragma unroll
            for (int e = 0; e < 4; ++e) p[e] = zero ? (short)0 : f2bf(f[e]);
            *(short4v*)&lx[tt][m][k0 + u] = p;
        }
    }
    __syncthreads();

    int lane = tid & 63, w = tid >> 6;
    int ln = lane & 15, q = lane >> 4;

    short8 Af[4][4];  // [t][kchunk]
#pragma unroll
    for (int tt = 0; tt < 4; ++tt)
#pragma unroll
        for (int c = 0; c < 4; ++c)
            Af[tt][c] = *(const short8*)&lx[tt][ln][c * 32 + q * 8];

    for (int nt = 0; nt < 16; ++nt) {
        int tile = w * 16 + nt;
        short8 Bf[4];
#pragma unroll
        for (int c = 0; c < 4; ++c)
            Bf[c] = *(const short8*)(wih_frags + (((size_t)tile * 4 + c) * 64 + lane) * 16);
        float b = bias[tile * 16 + ln];
#pragma unroll
        for (int tt = 0; tt < 4; ++tt) {
            float4v acc = {b, b, b, b};
#pragma unroll
            for (int c = 0; c < 4; ++c)
                acc = __builtin_amdgcn_mfma_f32_16x16x32_bf16(Af[tt][c], Bf[c], acc, 0, 0, 0);
            short4v p;
#pragma unroll
            for (int r = 0; r < 4; ++r) p[r] = f2bf(acc[r]);
            *(short4v*)(xg + ((((size_t)(t0 + tt) * 4 + g) * 64 + tile) * 64 + lane) * 8) = p;
        }
    }
}

// ---------------------------------------------------------------------------
// Forward LSTM scan. Grid = 4 blocks (batch groups of 16), 512 threads (8 waves).
// W_hh_f bf16 fragments register-resident (64 frags/lane = 256 VGPR-equiv, -> AGPRs).
// Wave w owns gate N-tiles {w, w+8} + their f/g/o counterparts (+16/+32/+48 tiles),
// so the c/h update is wave-local. h round-trips through LDS as bf16 each step.
// ---------------------------------------------------------------------------
__global__ __launch_bounds__(512, 2) void lstm_scan(const char* __restrict__ whh_frags,
                                                    const char* __restrict__ xg,
                                                    float* __restrict__ hf_out) {
    __shared__ __align__(16) short hls[16][264];  // h bf16 [batch][H], +8 pad
    int tid = threadIdx.x;
    int lane = tid & 63, w = tid >> 6;
    int ln = lane & 15, q = lane >> 4;
    int g = blockIdx.x;

    const int jt0 = w, jt1 = w + 8;
    int tiles[8];  // i@jt0, i@jt1, f@jt0, f@jt1, g@jt0, g@jt1, o@jt0, o@jt1
#pragma unroll
    for (int blk = 0; blk < 4; ++blk) {
        tiles[2 * blk] = 16 * blk + jt0;
        tiles[2 * blk + 1] = 16 * blk + jt1;
    }

    // load W_hh fragments into registers (stay for the whole scan)
    short8 Wf[8][8];
#pragma unroll
    for (int ti = 0; ti < 8; ++ti)
#pragma unroll
        for (int c = 0; c < 8; ++c)
            Wf[ti][c] = *(const short8*)(whh_frags +
                                         (((size_t)tiles[ti] * 8 + c) * 64 + lane) * 16);

    float cst[2][4];
#pragma unroll
    for (int jt = 0; jt < 2; ++jt)
#pragma unroll
        for (int r = 0; r < 4; ++r) cst[jt][r] = 0.0f;

    // zero h
    {
        short* hp = &hls[0][0];
        for (int i = tid; i < 16 * 264; i += 512) hp[i] = 0;
    }
    __syncthreads();

    for (int t = 0; t < S_LEN; ++t) {
        // read h A-fragments (previous step's h)
        short8 Afr[8];
#pragma unroll
        for (int c = 0; c < 8; ++c)
            Afr[c] = *(const short8*)&hls[ln][c * 32 + q * 8];
        // stream xg for this step
        const char* xgb = xg + (((size_t)t * 4 + g) * 64) * 512;
        short4v xv[8];
#pragma unroll
        for (int ti = 0; ti < 8; ++ti)
            xv[ti] = *(const short4v*)(xgb + (size_t)tiles[ti] * 512 + (size_t)lane * 8);
        __syncthreads();  // all waves finished reading h before anyone overwrites it

        float4v acc[8];
#pragma unroll
        for (int ti = 0; ti < 8; ++ti)
#pragma unroll
            for (int r = 0; r < 4; ++r) acc[ti][r] = bf2f(xv[ti][r]);

        // chunk-major: 8 independent MFMA chains interleaved (no dep stalls)
#pragma unroll
        for (int c = 0; c < 8; ++c)
#pragma unroll
            for (int ti = 0; ti < 8; ++ti)
                acc[ti] = __builtin_amdgcn_mfma_f32_16x16x32_bf16(Afr[c], Wf[ti][c], acc[ti], 0, 0, 0);

        // activations in place: i,i,f,f sigmoid; g,g tanh; o,o sigmoid
#pragma unroll
        for (int ti = 0; ti < 8; ++ti)
#pragma unroll
            for (int r = 0; r < 4; ++r)
                acc[ti][r] = (ti == 4 || ti == 5) ? tanh_(acc[ti][r]) : sigm(acc[ti][r]);

        // cell update + h write (wave-local gates)
#pragma unroll
        for (int jt = 0; jt < 2; ++jt) {
#pragma unroll
            for (int r = 0; r < 4; ++r) {
                float iv = acc[0 + jt][r];
                float fv = acc[2 + jt][r];
                float gv = acc[4 + jt][r];
                float ov = acc[6 + jt][r];
                float cv = fv * cst[jt][r] + iv * gv;
                cst[jt][r] = cv;
                float hv = ov * tanh_(cv);
                int b = q * 4 + r;
                int j = (jt ? jt1 : jt0) * 16 + ln;
                hls[b][j] = f2bf(hv);
                if (t == S_LEN - 1)
                    hf_out[((size_t)g * 16 + b) * HDIM + j] = hv;
            }
        }
        __syncthreads();  // h(t) complete before next step reads it
    }
}

// ---------------------------------------------------------------------------
// Tail: backward cell at position S-1 (h0=c0=0 => W_hh_b unused) + output proj.
// One block per batch element; thread j handles hidden unit j.
// ---------------------------------------------------------------------------
__global__ __launch_bounds__(256) void tail_kernel(const int* __restrict__ seq,
                                                   const float* __restrict__ emb,
                                                   const float* __restrict__ wih_b,
                                                   const float* __restrict__ b_b,
                                                   const float* __restrict__ wout,
                                                   const float* __restrict__ b_out,
                                                   const float* __restrict__ hf,
                                                   float* __restrict__ out) {
    __shared__ float xs[EDIM];
    __shared__ float red[4];
    int b = blockIdx.x, tid = threadIdx.x;
    if (tid < EDIM) {
        int v = seq[(S_LEN - 1) * NBATCH + b];
        xs[tid] = (v == 0) ? 0.0f : emb[(size_t)v * EDIM + tid];
    }
    __syncthreads();

    int j = tid;  // 0..255 = hidden unit
    float si = b_b[j], sg = b_b[2 * HDIM + j], so = b_b[3 * HDIM + j];
    const float* wi = wih_b + (size_t)j * EDIM;
    const float* wg = wih_b + (size_t)(2 * HDIM + j) * EDIM;
    const float* wo = wih_b + (size_t)(3 * HDIM + j) * EDIM;
#pragma unroll 8
    for (int k = 0; k < EDIM; k += 4) {
        float4v x4 = *(const float4v*)&xs[k];
        float4v a = *(const float4v*)(wi + k);
        float4v c = *(const float4v*)(wg + k);
        float4v d = *(const float4v*)(wo + k);
#pragma unroll
        for (int e = 0; e < 4; ++e) {
            si += a[e] * x4[e];
            sg += c[e] * x4[e];
            so += d[e] * x4[e];
        }
    }
    float cc = sigm(si) * tanh_(sg);   // c = i*g   (f*c0 = 0)
    float hb = sigm(so) * tanh_(cc);   // h = o*tanh(c)
    float partial = hf[(size_t)b * HDIM + j] * wout[j] + hb * wout[HDIM + j];

    float val = partial;
#pragma unroll
    for (int off = 32; off > 0; off >>= 1) val += __shfl_down(val, off, 64);
    int lane = tid & 63, wv = tid >> 6;
    if (lane == 0) red[wv] = val;
    __syncthreads();
    if (tid == 0) out[b] = sigm(red[0] + red[1] + red[2] + red[3] + b_out[0]);
}

extern "C" void kernel_launch(void* const* d_in, const int* in_sizes, int n_in,
                              void* d_out, int out_size, void* d_ws, size_t ws_size,
                              hipStream_t stream) {
    const int* seq = (const int*)d_in[0];
    const float* emb = (const float*)d_in[1];
    const float* Wih_f = (const float*)d_in[2];
    const float* Whh_f = (const float*)d_in[3];
    const float* b_f = (const float*)d_in[4];
    const float* Wih_b = (const float*)d_in[5];
    // d_in[6] = W_hh_b: provably unused (backward scan's only needed output is its
    // step 0, where h0 = 0 so the recurrent term vanishes).
    const float* b_b = (const float*)d_in[7];
    const float* Wout = (const float*)d_in[8];
    const float* b_out = (const float*)d_in[9];
    float* out = (float*)d_out;
    char* ws = (char*)d_ws;

    // 1) weight fragments (bf16)
    prep_frags<<<dim3((64 * 8 * 64) / 256), 256, 0, stream>>>(Whh_f, ws + OFF_WHH, HDIM, 8, 64 * 8);
    prep_frags<<<dim3((64 * 4 * 64) / 256), 256, 0, stream>>>(Wih_f, ws + OFF_WIH, EDIM, 4, 64 * 4);
    // 2) forward input projections for all timesteps
    input_proj<<<dim3(S_LEN / 4, 4), 256, 0, stream>>>(seq, emb, ws + OFF_WIH, b_f, ws + OFF_XG);
    // 3) sequential forward scan (4 batch groups, 1 CU each)
    lstm_scan<<<dim3(4), 512, 0, stream>>>(ws + OFF_WHH, ws + OFF_XG, (float*)(ws + OFF_HF));
    // 4) backward single cell + output projection
    tail_kernel<<<dim3(NBATCH), 256, 0, stream>>>(seq, emb, Wih_b, b_b, Wout, b_out,
                                                  (const float*)(ws + OFF_HF), out);
}